// Round 11
// baseline (48.285 us; speedup 1.0000x reference)
//
#include <hip/hip_runtime.h>
#include <hip/hip_bf16.h>

// StackedPyrHourGlassLoss — round 11 (= round 10 resubmit; infra flake #4,
// same dead container — design still unmeasured).
// r6 stage structure (1 pb per 256-thr block, measured best 19.9 µs) with the
// finalize NODE removed: valid blocks atomicAdd fixed-point (num,den) into
// 16-way-SPREAD per-level accumulators (relaxed agent atomics, no fences);
// every block release-increments one of 64 padded completion counters; one
// extra poller block spins on the counters, then computes the loss inline.
// r5 post-mortem applied: no __threadfence (L2 writeback), no same-address
// RMW chain (spread counters: max chain 57; spread accs: max chain ~5).
// Graph = [memset 4.9 KB] + [single kernel].

constexpr int NBATCH = 2;
constexpr int EMB = 32;
constexpr int TGTC = 9;      // 1 gt + 8 affinity channels
constexpr int PZ = 5, PY = 15, PX = 15;
constexpr int P = PZ * PY * PX;   // 1125

constexpr int NBLK0 = NBATCH * 4 * 17 * 17;  // 2312
constexpr int NBLK1 = NBATCH * 4 * 9 * 9;    // 648
constexpr int NBLK2 = NBATCH * 4 * 9 * 9;    // 648
constexpr int NBLK_TOT = NBLK0 + NBLK1 + NBLK2;  // 3608

constexpr int NCNT = 64;         // spread completion counters
constexpr int CNT_STRIDE = 16;   // 64 B padding between counters
constexpr int NACC = 16;         // spread slots per accumulator
constexpr double FIX = 4294967296.0;   // 2^32 fixed-point scale

// d_ws layout: [0, 4096)           uint32 counters[64] @ 64B stride
//              [4096, 4096+768)    ull acc[3][2][16]   (n,d per level)
constexpr size_t WS_ZERO_BYTES = 4096 + 3 * 2 * NACC * 8;

__device__ __forceinline__ unsigned long long to_fixed(float x)
{
    // x in [0, 2250]; at 2^32 scale the grid-wide sum < 2^63
    return (unsigned long long)__double2ll_rn((double)x * FIX);
}

template <int D, int H, int W,
          int NB0, int NBH, int NBW,
          int SH, int SW,
          int DH, int DWIN,
          int OFFZ, int OFFY, int OFFX,
          int AFFB>
__device__ __forceinline__
void level_body(const int lbid,
                const float* __restrict__ pred,
                const int* __restrict__ tgt,
                const float* __restrict__ Wm,
                const float* __restrict__ bv,
                unsigned long long* __restrict__ accN,   // [NACC] spread
                unsigned long long* __restrict__ accD)   // [NACC] spread
{
    const int tid = threadIdx.x;

    int k  = lbid % NBW;
    int t1 = lbid / NBW;
    int j  = t1 % NBH;
    int t2 = t1 / NBH;
    int i  = t2 % NB0;
    int b  = t2 / NB0;

    const int HW = H * W;
    const int CH = D * HW;
    const int zc = OFFZ + i;           // z-stride is 1 at all levels
    const int yc = OFFY + j * SH;
    const int xc = OFFX + k * SW;
    const int cidx = zc * HW + yc * W + xc;

    __shared__ float s_emb[EMB];
    __shared__ int   s_c;
    __shared__ int   s_valid;

    if (tid == 0) {
        const int c = tgt[b * TGTC * CH + cidx];
        bool allaff = true;
        #pragma unroll
        for (int ch = 0; ch < 4; ++ch)
            allaff &= (tgt[(b * TGTC + AFFB + ch) * CH + cidx] != 0);
        s_c = c;
        s_valid = (c != 0) && allaff;
    }
    __syncthreads();

    if (!s_valid)
        return;                         // invalid: contributes nothing

    if (tid < EMB)
        s_emb[tid] = pred[(b * EMB + tid) * CH + cidx];
    __syncthreads();

    const int* __restrict__ gtb = tgt + b * TGTC * CH;  // gt channel
    const int c = s_c;

    float num = 0.0f, den = 0.0f;
    for (int o = tid; o < P; o += 256) {
        const int pz = o / (PY * PX);
        const int r  = o - pz * (PY * PX);
        const int py = r / PX;
        const int px = r - py * PX;

        float dot = bv[o];
        #pragma unroll
        for (int e = 0; e < EMB; ++e)
            dot = fmaf(s_emb[e], Wm[e * P + o], dot);
        // fast sigmoid (rel err ~1e-7; threshold 4.7e-2)
        float pp = __builtin_amdgcn_rcpf(1.0f + __expf(-dot));

        const int zb = i + pz;
        const int yb = j * SH + py * DH;
        const int xb = k * SW + px * DWIN;
        bool anyz = false, anyd = false;
        #pragma unroll
        for (int wy = 0; wy < DH; ++wy) {
            #pragma unroll
            for (int wx = 0; wx < DWIN; ++wx) {
                const int g = gtb[zb * HW + (yb + wy) * W + (xb + wx)];
                anyz |= (g == 0);
                anyd |= (g != c);
            }
        }
        float trg = (anyz || !anyd) ? 0.0f : 1.0f;
        if (anyz) pp = 0.0f;

        num = fmaf(pp, trg, num);
        den += pp * pp + trg * trg;
    }

    #pragma unroll
    for (int off = 32; off > 0; off >>= 1) {
        num += __shfl_xor(num, off);
        den += __shfl_xor(den, off);
    }
    __shared__ float sn[4], sd[4];
    if ((tid & 63) == 0) { sn[tid >> 6] = num; sd[tid >> 6] = den; }
    __syncthreads();
    if (tid == 0) {
        const float N_ = sn[0] + sn[1] + sn[2] + sn[3];
        const float D_ = sd[0] + sd[1] + sd[2] + sd[3];
        const int slot = lbid & (NACC - 1);
        __hip_atomic_fetch_add(accN + slot, to_fixed(N_),
                               __ATOMIC_RELAXED, __HIP_MEMORY_SCOPE_AGENT);
        __hip_atomic_fetch_add(accD + slot, to_fixed(D_),
                               __ATOMIC_RELAXED, __HIP_MEMORY_SCOPE_AGENT);
    }
}

__global__ __launch_bounds__(256)
void fused_kernel(const float* __restrict__ pred0, const int* __restrict__ tgt0,
                  const float* __restrict__ W0, const float* __restrict__ b0,
                  const float* __restrict__ pred1, const int* __restrict__ tgt1,
                  const float* __restrict__ W1, const float* __restrict__ b1,
                  const float* __restrict__ pred2, const int* __restrict__ tgt2,
                  const float* __restrict__ W2, const float* __restrict__ b2,
                  unsigned int* __restrict__ counters,       // [64] @ stride 16
                  unsigned long long* __restrict__ acc,      // [3][2][16]
                  float* __restrict__ out)
{
    const int gb = blockIdx.x;

    if (gb < NBLK_TOT) {
        if (gb < NBLK0) {
            // lvl0: 8,160,160  nb=(4,17,17) s=6 dws=4 off=(2,30,30) aff 5..8
            level_body<8, 160, 160, 4, 17, 17, 6, 6, 4, 4, 2, 30, 30, 5>(
                gb, pred0, tgt0, W0, b0, acc + 0 * NACC, acc + 1 * NACC);
        } else if (gb < NBLK0 + NBLK1) {
            // lvl1: 8,80,80  nb=(4,9,9) s=6 dws=2 off=(2,15,15) aff 1..4
            level_body<8, 80, 80, 4, 9, 9, 6, 6, 2, 2, 2, 15, 15, 1>(
                gb - NBLK0, pred1, tgt1, W1, b1, acc + 2 * NACC, acc + 3 * NACC);
        } else {
            // lvl2: 8,40,40  nb=(4,9,9) s=3 dws=1 off=(2,7,7) aff 1..4
            level_body<8, 40, 40, 4, 9, 9, 3, 3, 1, 1, 2, 7, 7, 1>(
                gb - NBLK0 - NBLK1, pred2, tgt2, W2, b2,
                acc + 4 * NACC, acc + 5 * NACC);
        }
        // completion notification: release orders the acc adds above
        if (threadIdx.x == 0)
            __hip_atomic_fetch_add(&counters[(gb & (NCNT - 1)) * CNT_STRIDE],
                                   1u, __ATOMIC_RELEASE,
                                   __HIP_MEMORY_SCOPE_AGENT);
        return;
    }

    // ---- poller block (blockIdx == NBLK_TOT): wave 0 only ----
    const int lane = threadIdx.x;
    if (lane >= 64) return;

    unsigned int s;
    do {
        unsigned int v = __hip_atomic_load(&counters[lane * CNT_STRIDE],
                                           __ATOMIC_ACQUIRE,
                                           __HIP_MEMORY_SCOPE_AGENT);
        s = v;
        #pragma unroll
        for (int off = 32; off > 0; off >>= 1)
            s += __shfl_xor(s, off);
        if (s < (unsigned)NBLK_TOT)
            __builtin_amdgcn_s_sleep(8);
    } while (s < (unsigned)NBLK_TOT);

    if (lane == 0) {
        double loss = 0.0;
        #pragma unroll
        for (int l = 0; l < 3; ++l) {
            unsigned long long n = 0ull, d = 0ull;
            #pragma unroll
            for (int t = 0; t < NACC; ++t) {
                n += __hip_atomic_load(acc + (2 * l + 0) * NACC + t,
                                       __ATOMIC_RELAXED, __HIP_MEMORY_SCOPE_AGENT);
                d += __hip_atomic_load(acc + (2 * l + 1) * NACC + t,
                                       __ATOMIC_RELAXED, __HIP_MEMORY_SCOPE_AGENT);
            }
            const double nd = (double)(long long)n / FIX;
            const double dd = (double)(long long)d / FIX;
            loss += -2.0 * nd / fmax(dd, 1e-6);
        }
        out[0] = (float)loss;
    }
}

extern "C" void kernel_launch(void* const* d_in, const int* in_sizes, int n_in,
                              void* d_out, int out_size, void* d_ws, size_t ws_size,
                              hipStream_t stream)
{
    const float* pred0 = (const float*)d_in[0];
    const int*   tgt0  = (const int*)  d_in[1];
    const float* W0    = (const float*)d_in[2];
    const float* b0    = (const float*)d_in[3];
    const float* pred1 = (const float*)d_in[4];
    const int*   tgt1  = (const int*)  d_in[5];
    const float* W1    = (const float*)d_in[6];
    const float* b1    = (const float*)d_in[7];
    const float* pred2 = (const float*)d_in[8];
    const int*   tgt2  = (const int*)  d_in[9];
    const float* W2    = (const float*)d_in[10];
    const float* b2    = (const float*)d_in[11];

    float* out = (float*)d_out;
    unsigned int* counters  = (unsigned int*)d_ws;
    unsigned long long* acc = (unsigned long long*)((char*)d_ws + 4096);

    hipMemsetAsync(d_ws, 0, WS_ZERO_BYTES, stream);

    fused_kernel<<<NBLK_TOT + 1, 256, 0, stream>>>(
        pred0, tgt0, W0, b0, pred1, tgt1, W1, b1, pred2, tgt2, W2, b2,
        counters, acc, out);
}

// Round 12
// 19.003 us; speedup vs baseline: 2.5410x; 2.5410x over previous
//
#include <hip/hip_runtime.h>
#include <hip/hip_bf16.h>

// StackedPyrHourGlassLoss — round 12.
// Back to the measured-best 2-node structure (r6: 19.9 µs). r5/r11 lesson
// (double-confirmed): per-block device-scope release/fence ops cost ~20 ns x
// 3608 serialized (77 µs) regardless of address spreading — single-kernel
// self-sync is dead on gfx950. Trims vs r6:
//  - validity + embedding via BLOCK-UNIFORM loads (compiler emits scalar
//    SMEM loads; no LDS, no barriers on the invalid path, one less barrier
//    on the valid path)
//  - finalize at 512 threads (3.5 float4 rounds over 3608 pairs).

constexpr int NBATCH = 2;
constexpr int EMB = 32;
constexpr int TGTC = 9;      // 1 gt + 8 affinity channels
constexpr int PZ = 5, PY = 15, PX = 15;
constexpr int P = PZ * PY * PX;   // 1125

constexpr int NBLK0 = NBATCH * 4 * 17 * 17;  // 2312
constexpr int NBLK1 = NBATCH * 4 * 9 * 9;    // 648
constexpr int NBLK2 = NBATCH * 4 * 9 * 9;    // 648
constexpr int NBLK_TOT = NBLK0 + NBLK1 + NBLK2;  // 3608

template <int D, int H, int W,
          int NB0, int NBH, int NBW,
          int SH, int SW,
          int DH, int DWIN,
          int OFFZ, int OFFY, int OFFX,
          int AFFB>
__device__ __forceinline__
void level_body(const int lbid,
                const float* __restrict__ pred,
                const int* __restrict__ tgt,
                const float* __restrict__ Wm,
                const float* __restrict__ bv,
                float* __restrict__ partials)
{
    const int tid = threadIdx.x;

    int k  = lbid % NBW;
    int t1 = lbid / NBW;
    int j  = t1 % NBH;
    int t2 = t1 / NBH;
    int i  = t2 % NB0;
    int b  = t2 / NB0;

    const int HW = H * W;
    const int CH = D * HW;
    const int zc = OFFZ + i;           // z-stride is 1 at all levels
    const int yc = OFFY + j * SH;
    const int xc = OFFX + k * SW;
    const int cidx = zc * HW + yc * W + xc;

    // ---- validity: all operands blockIdx-uniform -> scalar loads, no LDS,
    //      no barrier. Every thread computes the same result in registers.
    const int c = tgt[b * TGTC * CH + cidx];
    bool allaff = true;
    #pragma unroll
    for (int ch = 0; ch < 4; ++ch)
        allaff &= (tgt[(b * TGTC + AFFB + ch) * CH + cidx] != 0);
    const bool valid = (c != 0) && allaff;

    if (!valid) {
        if (tid == 0) {
            partials[2 * lbid]     = 0.0f;
            partials[2 * lbid + 1] = 0.0f;
        }
        return;                        // no barrier on the 94% path
    }

    // ---- embedding: 32 uniform loads -> registers (scalar file) ----
    float ev[EMB];
    #pragma unroll
    for (int e = 0; e < EMB; ++e)
        ev[e] = pred[(b * EMB + e) * CH + cidx];

    const int* __restrict__ gtb = tgt + b * TGTC * CH;  // gt channel

    float num = 0.0f, den = 0.0f;
    for (int o = tid; o < P; o += 256) {
        const int pz = o / (PY * PX);
        const int r  = o - pz * (PY * PX);
        const int py = r / PX;
        const int px = r - py * PX;

        float dot = bv[o];
        #pragma unroll
        for (int e = 0; e < EMB; ++e)
            dot = fmaf(ev[e], Wm[e * P + o], dot);
        // fast sigmoid (rel err ~1e-7; threshold 4.7e-2)
        float pp = __builtin_amdgcn_rcpf(1.0f + __expf(-dot));

        const int zb = i + pz;
        const int yb = j * SH + py * DH;
        const int xb = k * SW + px * DWIN;
        bool anyz = false, anyd = false;
        #pragma unroll
        for (int wy = 0; wy < DH; ++wy) {
            #pragma unroll
            for (int wx = 0; wx < DWIN; ++wx) {
                const int g = gtb[zb * HW + (yb + wy) * W + (xb + wx)];
                anyz |= (g == 0);
                anyd |= (g != c);
            }
        }
        float trg = (anyz || !anyd) ? 0.0f : 1.0f;
        if (anyz) pp = 0.0f;

        num = fmaf(pp, trg, num);
        den += pp * pp + trg * trg;
    }

    // wave butterfly then one LDS round across the 4 waves (valid path only)
    #pragma unroll
    for (int off = 32; off > 0; off >>= 1) {
        num += __shfl_xor(num, off);
        den += __shfl_xor(den, off);
    }
    __shared__ float sn[4], sd[4];
    if ((tid & 63) == 0) { sn[tid >> 6] = num; sd[tid >> 6] = den; }
    __syncthreads();
    if (tid == 0) {
        partials[2 * lbid]     = sn[0] + sn[1] + sn[2] + sn[3];
        partials[2 * lbid + 1] = sd[0] + sd[1] + sd[2] + sd[3];
    }
}

__global__ __launch_bounds__(256)
void stage_kernel(const float* __restrict__ pred0, const int* __restrict__ tgt0,
                  const float* __restrict__ W0, const float* __restrict__ b0,
                  const float* __restrict__ pred1, const int* __restrict__ tgt1,
                  const float* __restrict__ W1, const float* __restrict__ b1,
                  const float* __restrict__ pred2, const int* __restrict__ tgt2,
                  const float* __restrict__ W2, const float* __restrict__ b2,
                  float* __restrict__ partials)
{
    const int gb = blockIdx.x;
    if (gb < NBLK0) {
        // lvl0: 8,160,160  nb=(4,17,17) stride=6 dws=4 off=(2,30,30) aff 5..8
        level_body<8, 160, 160, 4, 17, 17, 6, 6, 4, 4, 2, 30, 30, 5>(
            gb, pred0, tgt0, W0, b0, partials);
    } else if (gb < NBLK0 + NBLK1) {
        // lvl1: 8,80,80  nb=(4,9,9) stride=6 dws=2 off=(2,15,15) aff 1..4
        level_body<8, 80, 80, 4, 9, 9, 6, 6, 2, 2, 2, 15, 15, 1>(
            gb - NBLK0, pred1, tgt1, W1, b1, partials + 2 * NBLK0);
    } else {
        // lvl2: 8,40,40  nb=(4,9,9) stride=3 dws=1 off=(2,7,7) aff 1..4
        level_body<8, 40, 40, 4, 9, 9, 3, 3, 1, 1, 2, 7, 7, 1>(
            gb - NBLK0 - NBLK1, pred2, tgt2, W2, b2,
            partials + 2 * (NBLK0 + NBLK1));
    }
}

__global__ __launch_bounds__(512)
void finalize_kernel(const float* __restrict__ partials, float* __restrict__ out)
{
    const int tid = threadIdx.x;

    // 3608 float2 pairs = 1804 float4; level boundaries (2312, 2960) are
    // even pb indices -> every float4 is level-pure.
    constexpr int NF4 = NBLK_TOT / 2;          // 1804
    constexpr int B01 = NBLK0 / 2;             // 1156
    constexpr int B12 = (NBLK0 + NBLK1) / 2;   // 1480

    float n0 = 0.f, d0 = 0.f, n1 = 0.f, d1 = 0.f, n2 = 0.f, d2 = 0.f;
    const float4* p4 = (const float4*)partials;
    for (int p = tid; p < NF4; p += 512) {
        const float4 v = p4[p];
        if (p < B01)      { n0 += v.x + v.z; d0 += v.y + v.w; }
        else if (p < B12) { n1 += v.x + v.z; d1 += v.y + v.w; }
        else              { n2 += v.x + v.z; d2 += v.y + v.w; }
    }

    #pragma unroll
    for (int off = 32; off > 0; off >>= 1) {
        n0 += __shfl_down(n0, off);  d0 += __shfl_down(d0, off);
        n1 += __shfl_down(n1, off);  d1 += __shfl_down(d1, off);
        n2 += __shfl_down(n2, off);  d2 += __shfl_down(d2, off);
    }
    __shared__ float s[8][6];
    if ((tid & 63) == 0) {
        const int w = tid >> 6;
        s[w][0] = n0; s[w][1] = d0; s[w][2] = n1;
        s[w][3] = d1; s[w][4] = n2; s[w][5] = d2;
    }
    __syncthreads();
    if (tid == 0) {
        float acc[6];
        #pragma unroll
        for (int q = 0; q < 6; ++q) {
            acc[q] = s[0][q];
            #pragma unroll
            for (int w = 1; w < 8; ++w) acc[q] += s[w][q];
        }
        float loss = 0.0f;
        loss += -2.0f * acc[0] / fmaxf(acc[1], 1e-6f);
        loss += -2.0f * acc[2] / fmaxf(acc[3], 1e-6f);
        loss += -2.0f * acc[4] / fmaxf(acc[5], 1e-6f);
        out[0] = loss;
    }
}

extern "C" void kernel_launch(void* const* d_in, const int* in_sizes, int n_in,
                              void* d_out, int out_size, void* d_ws, size_t ws_size,
                              hipStream_t stream)
{
    const float* pred0 = (const float*)d_in[0];
    const int*   tgt0  = (const int*)  d_in[1];
    const float* W0    = (const float*)d_in[2];
    const float* b0    = (const float*)d_in[3];
    const float* pred1 = (const float*)d_in[4];
    const int*   tgt1  = (const int*)  d_in[5];
    const float* W1    = (const float*)d_in[6];
    const float* b1    = (const float*)d_in[7];
    const float* pred2 = (const float*)d_in[8];
    const int*   tgt2  = (const int*)  d_in[9];
    const float* W2    = (const float*)d_in[10];
    const float* b2    = (const float*)d_in[11];

    float* out      = (float*)d_out;
    float* partials = (float*)d_ws;   // 3608 (num,den) pairs

    stage_kernel<<<NBLK_TOT, 256, 0, stream>>>(
        pred0, tgt0, W0, b0, pred1, tgt1, W1, b1, pred2, tgt2, W2, b2,
        partials);
    finalize_kernel<<<1, 512, 0, stream>>>(partials, out);
}